// Round 1
// baseline (6526.756 us; speedup 1.0000x reference)
//
#include <hip/hip_runtime.h>
#include <hip/hip_bf16.h>

// LSTM caption classifier: B=4096, T=22, E=H=300, V=30000, out=[B,2] f32.
// One workgroup (256 thr) owns 16 batch rows; grid=256 (1 wg/CU).
// Per step: stage x=embed[tok] into LDS, stream W=[W_ih|W_hh] (2.88MB, L2-hot)
// through LDS in 20-wide k-chunks, fp32 register-tiled GEMM (8r x 3jh x 4gates
// per thread), gates+c+h update fully in registers/LDS. cap_len masks updates.

#define TT 22
#define HH 300
#define KC 20
#define NCH 30   // 600 / KC

__device__ __forceinline__ float sigm(float x) {
    return 1.0f / (1.0f + __expf(-x));
}
__device__ __forceinline__ float tanh_f(float x) {
    float ax = fabsf(x);
    float e = __expf(-2.0f * ax);
    float t = (1.0f - e) / (1.0f + e);
    return copysignf(t, x);
}

__global__ __launch_bounds__(256, 1)
void lstm_cls_kernel(const int* __restrict__ cap, const int* __restrict__ cap_len,
                     const float* __restrict__ embed,
                     const float* __restrict__ W_ih, const float* __restrict__ W_hh,
                     const float* __restrict__ b_ih, const float* __restrict__ b_hh,
                     const float* __restrict__ v_wn, const float* __restrict__ g_wn,
                     const float* __restrict__ b_cls, float* __restrict__ out)
{
    __shared__ float xh[16][604];    // [r][0..299]=x_t, [300..599]=h (pad to 604)
    __shared__ float wt[1200][KC];   // staged W chunk (col-major rows, stride 20)
    __shared__ float bsum[1200];     // b_ih + b_hh
    __shared__ float scaleS[2];      // g / ||v||
    __shared__ int   tokS[16];
    __shared__ int   lenS[16];
    __shared__ int   maxlenS;

    const int tid  = threadIdx.x;
    const int wg   = blockIdx.x;
    const int row0 = wg * 16;

    const int wave = tid >> 6;       // 0..3: owns jh range [75*wave, 75*wave+75)
    const int lane = tid & 63;
    const int rl   = lane >> 5;      // 0..1: row group (rows rl*8 .. rl*8+7)
    const int cl   = lane & 31;      // 0..31: col lane (only cl<25 active)
    const bool colActive = (cl < 25);

    int jh[3];
    #pragma unroll
    for (int q = 0; q < 3; ++q) {
        int j = wave * 75 + q * 25 + cl;
        jh[q] = j > 299 ? 299 : j;   // clamp only matters for inactive lanes
    }

    // ---- setup ----
    if (tid < 16) lenS[tid] = cap_len[row0 + tid];
    if (tid < 2) {
        float s = 0.f;
        for (int k = 0; k < HH; ++k) { float v = v_wn[tid * HH + k]; s += v * v; }
        scaleS[tid] = g_wn[tid] * rsqrtf(s);
    }
    if (tid == 0) {
        int m = 0;
        for (int r = 0; r < 16; ++r) { int L = cap_len[row0 + r]; m = L > m ? L : m; }
        maxlenS = m;
    }
    for (int u = tid; u < 1200; u += 256) bsum[u] = b_ih[u] + b_hh[u];
    for (int u = tid; u < 16 * 76; u += 256) {      // zero h region (+pad)
        int r = u / 76, k4 = u % 76;
        *(float4*)&xh[r][300 + k4 * 4] = make_float4(0.f, 0.f, 0.f, 0.f);
    }
    __syncthreads();
    const int maxlen = maxlenS;

    float c[8][3];
    #pragma unroll
    for (int i = 0; i < 8; ++i)
        #pragma unroll
        for (int q = 0; q < 3; ++q) c[i][q] = 0.f;

    #pragma unroll 1
    for (int t = 0; t < maxlen; ++t) {
        if (tid < 16) tokS[tid] = cap[(row0 + tid) * TT + t];
        __syncthreads();   // tokens visible; prev-step h writes visible

        // stage x_t = embed[tok] (rows are 16B aligned: 300*4B)
        for (int u = tid; u < 16 * 75; u += 256) {
            int r = u / 75, k4 = u % 75;
            *(float4*)&xh[r][k4 * 4] =
                *(const float4*)&embed[(size_t)tokS[r] * HH + k4 * 4];
        }

        // init accumulators with biases
        float acc[8][3][4];
        #pragma unroll
        for (int q = 0; q < 3; ++q)
            #pragma unroll
            for (int g = 0; g < 4; ++g) {
                float b = bsum[g * 300 + jh[q]];
                #pragma unroll
                for (int i = 0; i < 8; ++i) acc[i][q][g] = b;
            }
        __syncthreads();   // x staged

        #pragma unroll 1
        for (int ch = 0; ch < NCH; ++ch) {
            const int kc = ch * KC;
            // stage W chunk: wt[col][0..19] = Wcat[col][kc..kc+19]
            for (int u = tid; u < 1200 * 5; u += 256) {
                int col = u / 5, t4 = u % 5;
                int kk = kc + t4 * 4;
                float4 v;
                if (kk < 300) v = *(const float4*)&W_ih[(size_t)col * HH + kk];
                else          v = *(const float4*)&W_hh[(size_t)col * HH + (kk - 300)];
                *(float4*)&wt[col][t4 * 4] = v;
            }
            __syncthreads();
            // consume: acc[i][q][g] += xh[row][kc+k] * wt[g*300+jh[q]][k]
            #pragma unroll
            for (int k4 = 0; k4 < 5; ++k4) {
                float4 xf[8];
                #pragma unroll
                for (int i = 0; i < 8; ++i)
                    xf[i] = *(const float4*)&xh[rl * 8 + i][kc + k4 * 4];
                #pragma unroll
                for (int q = 0; q < 3; ++q)
                    #pragma unroll
                    for (int g = 0; g < 4; ++g) {
                        float4 wf = *(const float4*)&wt[g * 300 + jh[q]][k4 * 4];
                        #pragma unroll
                        for (int i = 0; i < 8; ++i) {
                            acc[i][q][g] = fmaf(xf[i].x, wf.x, acc[i][q][g]);
                            acc[i][q][g] = fmaf(xf[i].y, wf.y, acc[i][q][g]);
                            acc[i][q][g] = fmaf(xf[i].z, wf.z, acc[i][q][g]);
                            acc[i][q][g] = fmaf(xf[i].w, wf.w, acc[i][q][g]);
                        }
                    }
            }
            __syncthreads();
        }

        // update h, c (masked by cap_len; h frozen after len -> last hidden kept)
        if (colActive) {
            #pragma unroll
            for (int i = 0; i < 8; ++i) {
                int r = rl * 8 + i;
                if (t < lenS[r]) {
                    #pragma unroll
                    for (int q = 0; q < 3; ++q) {
                        float ii = sigm(acc[i][q][0]);
                        float ff = sigm(acc[i][q][1]);
                        float gg = tanh_f(acc[i][q][2]);
                        float oo = sigm(acc[i][q][3]);
                        float cn = ff * c[i][q] + ii * gg;
                        c[i][q] = cn;
                        xh[r][300 + jh[q]] = oo * tanh_f(cn);
                    }
                }
            }
        }
        // top-of-loop barrier separates these writes from next-step reads
    }
    __syncthreads();

    // head: out[r][cls] = b_cls[cls] + sum_k (g/||v||) * v[cls][k] * h[r][k]
    if (tid < 32) {
        int r = tid >> 1, cls = tid & 1;
        float s = b_cls[cls];
        float sc = scaleS[cls];
        for (int k = 0; k < HH; ++k)
            s += sc * v_wn[cls * HH + k] * xh[r][300 + k];
        out[(size_t)(row0 + r) * 2 + cls] = s;
    }
}

extern "C" void kernel_launch(void* const* d_in, const int* in_sizes, int n_in,
                              void* d_out, int out_size, void* d_ws, size_t ws_size,
                              hipStream_t stream) {
    const int*   cap     = (const int*)  d_in[0];
    const int*   cap_len = (const int*)  d_in[1];
    const float* embed   = (const float*)d_in[2];
    const float* W_ih    = (const float*)d_in[3];
    const float* W_hh    = (const float*)d_in[4];
    const float* b_ih    = (const float*)d_in[5];
    const float* b_hh    = (const float*)d_in[6];
    const float* v_wn    = (const float*)d_in[7];
    const float* g_wn    = (const float*)d_in[8];
    const float* b_cls   = (const float*)d_in[9];
    float* out = (float*)d_out;

    lstm_cls_kernel<<<256, 256, 0, stream>>>(cap, cap_len, embed, W_ih, W_hh,
                                             b_ih, b_hh, v_wn, g_wn, b_cls, out);
}

// Round 2
// 881.269 us; speedup vs baseline: 7.4061x; 7.4061x over previous
//
#include <hip/hip_runtime.h>
#include <hip/hip_fp16.h>

// LSTM caption classifier via fp16 MFMA. B=4096, T=22, E=H=300.
// prep_w: W=[W_ih|W_hh] fp32 -> Wc fp16 [1216][608] in d_ws, gate blocks
//   padded 300->304 cols so each gate = 19 exact 16-wide N-tiles.
// lstm_mfma: 128 wgs x 32 rows, 256 thr (4 waves). Per step: stage x fp16 in
//   LDS, K-loop mfma_f32_16x16x32_f16 (A from LDS, B direct global from
//   L2-hot Wc), gate nonlinearities in-register (i/f/g/o same lane), c fp32
//   in VGPRs, h fp16 back to LDS. cap_len freezes rows -> last hidden kept.

#define TT 22

typedef _Float16 f16;
typedef _Float16 f16x4 __attribute__((ext_vector_type(4)));
typedef _Float16 f16x8 __attribute__((ext_vector_type(8)));
typedef float    f32x4 __attribute__((ext_vector_type(4)));

#define WSTR 608   // Wc row stride (halves): K = 600 + 8 zero-pad
#define ASTR 616   // A row stride (halves): 608 + 8 pad (bank spread)
#define NROW 32    // batch rows per wg
#define NWG  128

__device__ __forceinline__ float sigm(float x) { return 1.0f / (1.0f + __expf(-x)); }
__device__ __forceinline__ float tanh_f(float x) {
    float ax = fabsf(x);
    float e = __expf(-2.0f * ax);
    return copysignf((1.0f - e) / (1.0f + e), x);
}

__global__ void prep_w(const float* __restrict__ Wih, const float* __restrict__ Whh,
                       f16* __restrict__ Wc) {
    int jp = blockIdx.x;            // 0..1215 = gate*304 + jh
    int gate = jp / 304;
    int jh = jp - gate * 304;
    bool valid = jh < 300;
    int j = gate * 300 + jh;        // original row in [4H]
    for (int k = threadIdx.x; k < WSTR; k += 256) {
        float v = 0.f;
        if (valid) {
            if (k < 300)      v = Wih[(size_t)j * 300 + k];
            else if (k < 600) v = Whh[(size_t)j * 300 + (k - 300)];
        }
        Wc[(size_t)jp * WSTR + k] = (f16)v;
    }
}

__global__ __launch_bounds__(256, 1)
void lstm_mfma(const int* __restrict__ cap, const int* __restrict__ cap_len,
               const float* __restrict__ embed,
               const float* __restrict__ b_ih, const float* __restrict__ b_hh,
               const float* __restrict__ v_wn, const float* __restrict__ g_wn,
               const float* __restrict__ b_cls,
               const f16* __restrict__ Wc, float* __restrict__ out)
{
    __shared__ __align__(16) f16 Ald[NROW][ASTR];  // [r][0..299]=x, [300..599]=h, rest 0
    __shared__ int tokAll[NROW][TT];
    __shared__ int lenS[NROW];
    __shared__ float scaleS[2];
    __shared__ int maxlenS;

    const int tid  = threadIdx.x;
    const int row0 = blockIdx.x * NROW;
    const int wv   = tid >> 6;     // wave 0..3: owns jh-tiles jt = wv + 4s
    const int ln   = tid & 63;
    const int c    = ln & 15;      // A-row / B-col within tile
    const int kg   = ln >> 4;      // k-group (8 halves each)

    // ---- setup ----
    if (tid < NROW) lenS[tid] = cap_len[row0 + tid];
    if (tid < 2) {
        float s = 0.f;
        for (int k = 0; k < 300; ++k) { float v = v_wn[tid * 300 + k]; s += v * v; }
        scaleS[tid] = g_wn[tid] * rsqrtf(s);
    }
    if (tid == 0) {
        int m = 0;
        for (int r = 0; r < NROW; ++r) { int L = cap_len[row0 + r]; m = L > m ? L : m; }
        maxlenS = m;
    }
    for (int u = tid; u < NROW * TT; u += 256) {
        int r = u / TT, t = u % TT;
        tokAll[r][t] = cap[(size_t)(row0 + r) * TT + t];
    }
    // zero h + pad region: halves [300, 616) per row (79 x 8B)
    for (int u = tid; u < NROW * 79; u += 256) {
        int r = u / 79, q = u - r * 79;
        *(uint2*)&Ald[r][300 + q * 4] = make_uint2(0u, 0u);
    }

    // bias per (s,g): depends only on output column
    float biasr[5][4];
    #pragma unroll
    for (int s = 0; s < 5; ++s) {
        int jt = wv + 4 * s;
        #pragma unroll
        for (int g = 0; g < 4; ++g) {
            float b = 0.f;
            if (jt < 19) {
                int jh = jt * 16 + c;
                if (jh < 300) { int j = g * 300 + jh; b = b_ih[j] + b_hh[j]; }
            }
            biasr[s][g] = b;
        }
    }
    __syncthreads();
    const int maxlen = maxlenS;

    int lenr[2][4];
    #pragma unroll
    for (int m = 0; m < 2; ++m)
        #pragma unroll
        for (int rg = 0; rg < 4; ++rg) lenr[m][rg] = lenS[m * 16 + kg * 4 + rg];

    float cst[2][5][4] = {};   // cell state, fp32, lane-owned

    const f16* ab0 = &Ald[c][kg * 8];
    const f16* ab1 = &Ald[16 + c][kg * 8];
    const f16* wb  = Wc + (size_t)c * WSTR + kg * 8;

    #pragma unroll 1
    for (int t = 0; t < maxlen; ++t) {
        // stage x_t fp16 into LDS (32 rows x 300)
        {
            int r = tid >> 3;
            const float* erow = embed + (size_t)tokAll[r][t] * 300;
            #pragma unroll 1
            for (int q = (tid & 7); q < 75; q += 8) {
                float4 v = *(const float4*)(erow + q * 4);
                f16x4 hv; hv.x = (f16)v.x; hv.y = (f16)v.y; hv.z = (f16)v.z; hv.w = (f16)v.w;
                *(f16x4*)&Ald[r][q * 4] = hv;
            }
        }
        __syncthreads();   // x staged; prev h writes visible

        f32x4 acc[2][5][4];
        #pragma unroll
        for (int m = 0; m < 2; ++m)
            #pragma unroll
            for (int s = 0; s < 5; ++s)
                #pragma unroll
                for (int g = 0; g < 4; ++g) {
                    float b = biasr[s][g];
                    f32x4 bv = {b, b, b, b};
                    acc[m][s][g] = bv;
                }

        #pragma unroll 1
        for (int kt = 0; kt < 19; ++kt) {
            f16x8 a0 = *(const f16x8*)(ab0 + kt * 32);
            f16x8 a1 = *(const f16x8*)(ab1 + kt * 32);
            #pragma unroll
            for (int s = 0; s < 5; ++s) {
                int jt = wv + 4 * s;
                int jtc = jt < 19 ? jt : 18;   // wave 3 s=4: harmless duplicate
                #pragma unroll
                for (int g = 0; g < 4; ++g) {
                    f16x8 b = *(const f16x8*)(wb + (size_t)(16 * (g * 19 + jtc)) * WSTR + kt * 32);
                    acc[0][s][g] = __builtin_amdgcn_mfma_f32_16x16x32_f16(a0, b, acc[0][s][g], 0, 0, 0);
                    acc[1][s][g] = __builtin_amdgcn_mfma_f32_16x16x32_f16(a1, b, acc[1][s][g], 0, 0, 0);
                }
            }
        }
        __syncthreads();   // all waves done reading A before h rewrite

        // gate nonlinearities + state update (i/f/g/o are same-lane registers)
        #pragma unroll
        for (int m = 0; m < 2; ++m)
            #pragma unroll
            for (int s = 0; s < 5; ++s) {
                int jt = wv + 4 * s;
                if (jt < 19) {
                    int jh = jt * 16 + c;
                    #pragma unroll
                    for (int rg = 0; rg < 4; ++rg) {
                        int row = m * 16 + kg * 4 + rg;
                        bool upd = (t < lenr[m][rg]);
                        float iv = sigm(acc[m][s][0][rg]);
                        float fv = sigm(acc[m][s][1][rg]);
                        float gv = tanh_f(acc[m][s][2][rg]);
                        float ov = sigm(acc[m][s][3][rg]);
                        float cn = fv * cst[m][s][rg] + iv * gv;
                        cn = upd ? cn : cst[m][s][rg];
                        cst[m][s][rg] = cn;
                        if (upd && jh < 300)
                            Ald[row][300 + jh] = (f16)(ov * tanh_f(cn));
                    }
                }
            }
    }
    __syncthreads();

    // weight-normed head: out[r][cls] = b + (g/||v||) * <v[cls], h[r]>
    if (tid < 64) {
        int r = tid >> 1, cls = tid & 1;
        float s = b_cls[cls], sc = scaleS[cls];
        for (int k = 0; k < 300; ++k)
            s += sc * v_wn[cls * 300 + k] * (float)Ald[r][300 + k];
        out[(size_t)(row0 + r) * 2 + cls] = s;
    }
}

extern "C" void kernel_launch(void* const* d_in, const int* in_sizes, int n_in,
                              void* d_out, int out_size, void* d_ws, size_t ws_size,
                              hipStream_t stream) {
    const int*   cap     = (const int*)  d_in[0];
    const int*   cap_len = (const int*)  d_in[1];
    const float* embed   = (const float*)d_in[2];
    const float* W_ih    = (const float*)d_in[3];
    const float* W_hh    = (const float*)d_in[4];
    const float* b_ih    = (const float*)d_in[5];
    const float* b_hh    = (const float*)d_in[6];
    const float* v_wn    = (const float*)d_in[7];
    const float* g_wn    = (const float*)d_in[8];
    const float* b_cls   = (const float*)d_in[9];
    float* out = (float*)d_out;
    f16* Wc = (f16*)d_ws;   // 1216*608*2 B = 1.48 MB

    prep_w<<<1216, 256, 0, stream>>>(W_ih, W_hh, Wc);
    lstm_mfma<<<NWG, 256, 0, stream>>>(cap, cap_len, embed, b_ih, b_hh,
                                       v_wn, g_wn, b_cls, Wc, out);
}

// Round 3
// 747.507 us; speedup vs baseline: 8.7314x; 1.1789x over previous
//
#include <hip/hip_runtime.h>
#include <hip/hip_fp16.h>

// Weight-stationary LSTM classifier. B=4096(+64 pad), T=22, E=H=300.
// Grid 247 = 13 mb (320 rows) x 19 nb (16 jh-cols x 4 gates). Each wg keeps
// its W block (64 cols x 608 k fp16 = 79KB) in LDS for all 22 steps.
// Per step: gates = A @ W (A = [x|h] fp16 from global double-buffer),
// in-register i/f/g/o update (gate = acc register index), h kept in regs AND
// written to the other buffer; one device-scope barrier per step.
// d_ws: [0..256) barrier counter, then 2 x 4160x608 fp16 buffers (10.1 MB).

#define TT 22
#define NB 19
#define MBC 13
#define NWG (NB * MBC)          // 247
#define XSTR 608                 // halves per A row (300 x | 300 h | 8 pad)
#define WLS 616                  // LDS W col stride (halves)
#define BUFROWS 4160
#define BUFELT ((size_t)BUFROWS * XSTR)
#define STEPS 22

typedef _Float16 f16;
typedef _Float16 f16x8 __attribute__((ext_vector_type(8)));
typedef float    f32x4 __attribute__((ext_vector_type(4)));

__device__ __forceinline__ float sigm(float x) { return 1.0f / (1.0f + __expf(-x)); }
__device__ __forceinline__ float tanh_f(float x) {
    float ax = fabsf(x);
    float e = __expf(-2.0f * ax);
    return copysignf((1.0f - e) / (1.0f + e), x);
}

__global__ __launch_bounds__(256, 1)
void lstm_ws(const int* __restrict__ cap, const int* __restrict__ cap_len,
             const float* __restrict__ embed,
             const float* __restrict__ Wih, const float* __restrict__ Whh,
             const float* __restrict__ bih, const float* __restrict__ bhh,
             const float* __restrict__ v_wn, const float* __restrict__ g_wn,
             const float* __restrict__ b_cls,
             f16* __restrict__ buf0, f16* __restrict__ buf1,
             unsigned* __restrict__ cnt, float* __restrict__ out)
{
    __shared__ f16 Wl[64 * WLS];     // 78.8 KB, stationary weights
    __shared__ int capS[17][TT];
    __shared__ float scaleS[2];

    const int tid = threadIdx.x;
    const int wg  = blockIdx.x;
    const int mb  = wg / NB;
    const int nb  = wg - mb * NB;
    const int mrow0 = mb * 320;

    const int wv = tid >> 6, ln = tid & 63, c = ln & 15, kg = ln >> 4;

    // ---- W block -> LDS (fp32 -> fp16), cols = g*16+cc, k-major ----
    for (int u = tid; u < 64 * 76; u += 256) {
        int col = u / 76, k8 = u - col * 76;
        int g = col >> 4, cc = col & 15;
        int jh = nb * 16 + cc;
        int j = g * 300 + jh;
        f16x8 v;
        #pragma unroll
        for (int i = 0; i < 8; ++i) {
            int k = k8 * 8 + i;
            float x = 0.f;
            if (jh < 300) {
                if (k < 300)      x = Wih[(size_t)j * 300 + k];
                else if (k < 600) x = Whh[(size_t)j * 300 + (k - 300)];
            }
            v[i] = (f16)x;
        }
        *(f16x8*)&Wl[col * WLS + k8 * 8] = v;
    }

    // tokens for the rows this wg stages (17 rows of its mb block)
    const int srow0 = nb * 17;
    for (int u = tid; u < 17 * TT; u += 256) {
        int rl = u / TT, t = u - rl * TT;
        int grow = mrow0 + srow0 + rl;
        capS[rl][t] = (srow0 + rl < 320 && grow < 4096) ? cap[(size_t)grow * TT + t] : 0;
    }
    if (tid < 2) {
        float s = 0.f;
        for (int k = 0; k < 300; ++k) { float v = v_wn[tid * 300 + k]; s += v * v; }
        scaleS[tid] = g_wn[tid] * rsqrtf(s);
    }
    __syncthreads();

    // ---- x staging helper: embed[tok] fp32 -> fp16 into buf ----
    auto stage_x = [&](int t, f16* bufn) {
        for (int u = tid; u < 17 * 38; u += 256) {
            int rl = u / 38, ch = u - rl * 38;
            int lrow = srow0 + rl;
            int grow = mrow0 + lrow;
            if (lrow >= 320 || grow >= 4096) continue;
            const float* er = embed + (size_t)capS[rl][t] * 300;
            f16* dst = bufn + (size_t)grow * XSTR;
            int k0 = ch * 8;
            if (ch < 37) {
                float4 a = *(const float4*)(er + k0);
                float4 b = *(const float4*)(er + k0 + 4);
                f16x8 v;
                v[0] = (f16)a.x; v[1] = (f16)a.y; v[2] = (f16)a.z; v[3] = (f16)a.w;
                v[4] = (f16)b.x; v[5] = (f16)b.y; v[6] = (f16)b.z; v[7] = (f16)b.w;
                *(f16x8*)(dst + k0) = v;
            } else {
                #pragma unroll
                for (int i = 0; i < 4; ++i) dst[296 + i] = (f16)er[296 + i];
            }
        }
    };
    stage_x(0, buf0);

    // per-lane constants
    int aidx[5];
    #pragma unroll
    for (int m = 0; m < 5; ++m) {
        int row = mrow0 + (wv * 5 + m) * 16 + c;
        aidx[m] = row * XSTR + kg * 8;
    }
    int bbase[4];
    #pragma unroll
    for (int g = 0; g < 4; ++g) bbase[g] = (g * 16 + c) * WLS + kg * 8;

    const int jh = nb * 16 + c;
    float bias[4];
    #pragma unroll
    for (int g = 0; g < 4; ++g) {
        float b = 0.f;
        if (jh < 300) { int j = g * 300 + jh; b = bih[j] + bhh[j]; }
        bias[g] = b;
    }
    int lenr[5][4];
    #pragma unroll
    for (int m = 0; m < 5; ++m) {
        int rb = mrow0 + (wv * 5 + m) * 16 + kg * 4;
        #pragma unroll
        for (int rg = 0; rg < 4; ++rg) {
            int row = rb + rg;
            lenr[m][rg] = (row < 4096) ? cap_len[row] : 0;
        }
    }

    float cst[5][4] = {};
    float hreg[5][4] = {};

    unsigned bk = 0;
    auto gbar = [&]() {
        ++bk;
        __syncthreads();
        if (tid == 0) {
            __hip_atomic_fetch_add(cnt, 1u, __ATOMIC_RELEASE, __HIP_MEMORY_SCOPE_AGENT);
            unsigned tgt = bk * NWG;
            while (__hip_atomic_load(cnt, __ATOMIC_RELAXED, __HIP_MEMORY_SCOPE_AGENT) < tgt)
                __builtin_amdgcn_s_sleep(2);
            (void)__hip_atomic_load(cnt, __ATOMIC_ACQUIRE, __HIP_MEMORY_SCOPE_AGENT);
        }
        __syncthreads();
    };

    gbar();   // x0 visible everywhere

    #pragma unroll 1
    for (int t = 0; t < STEPS; ++t) {
        f16* bufc = (t & 1) ? buf1 : buf0;
        f16* bufn = (t & 1) ? buf0 : buf1;

        f32x4 acc[5][4];
        #pragma unroll
        for (int m = 0; m < 5; ++m)
            #pragma unroll
            for (int g = 0; g < 4; ++g) {
                float b = bias[g];
                f32x4 bv = {b, b, b, b};
                acc[m][g] = bv;
            }

        #pragma unroll
        for (int kt = 0; kt < 19; ++kt) {
            f16x8 av[5];
            #pragma unroll
            for (int m = 0; m < 5; ++m)
                av[m] = *(const f16x8*)(bufc + aidx[m] + kt * 32);
            #pragma unroll
            for (int g = 0; g < 4; ++g) {
                f16x8 bv = *(const f16x8*)&Wl[bbase[g] + kt * 32];
                #pragma unroll
                for (int m = 0; m < 5; ++m)
                    acc[m][g] = __builtin_amdgcn_mfma_f32_16x16x32_f16(av[m], bv, acc[m][g], 0, 0, 0);
            }
        }

        // gate update (i/f/g/o same lane, different acc regs) + h store
        #pragma unroll
        for (int m = 0; m < 5; ++m) {
            #pragma unroll
            for (int rg = 0; rg < 4; ++rg) {
                bool upd = (t < lenr[m][rg]);
                float iv = sigm(acc[m][0][rg]);
                float fv = sigm(acc[m][1][rg]);
                float gv = tanh_f(acc[m][2][rg]);
                float ov = sigm(acc[m][3][rg]);
                float cn = fv * cst[m][rg] + iv * gv;
                cn = upd ? cn : cst[m][rg];
                cst[m][rg] = cn;
                float hn = ov * tanh_f(cn);
                hreg[m][rg] = upd ? hn : hreg[m][rg];
            }
            if (jh < 300) {
                int rb = mrow0 + (wv * 5 + m) * 16 + kg * 4;
                #pragma unroll
                for (int rg = 0; rg < 4; ++rg)
                    bufn[(size_t)(rb + rg) * XSTR + 300 + jh] = (f16)hreg[m][rg];
            }
        }

        if (t + 1 < STEPS) stage_x(t + 1, bufn);
        gbar();
    }

    // ---- head: rows [wg*17, wg*17+17), 2 classes, 4 k-segments ----
    const f16* hb = buf0;   // final h lives in buf[22&1] = buf0
    for (int u = tid; u < 136; u += 256) {
        int rl = u >> 3, cls = (u >> 2) & 1, seg = u & 3;
        int grow = wg * 17 + rl;
        if (grow >= 4096) continue;
        float sc = scaleS[cls];
        const float* vr = v_wn + cls * 300 + seg * 75;
        const f16* hr = hb + (size_t)grow * XSTR + 300 + seg * 75;
        float s = 0.f;
        #pragma unroll 5
        for (int k = 0; k < 75; ++k) s += vr[k] * (float)hr[k];
        float part = sc * s + (seg == 0 ? b_cls[cls] : 0.f);
        atomicAdd(out + (size_t)grow * 2 + cls, part);
    }
}

extern "C" void kernel_launch(void* const* d_in, const int* in_sizes, int n_in,
                              void* d_out, int out_size, void* d_ws, size_t ws_size,
                              hipStream_t stream) {
    const int*   cap     = (const int*)  d_in[0];
    const int*   cap_len = (const int*)  d_in[1];
    const float* embed   = (const float*)d_in[2];
    const float* W_ih    = (const float*)d_in[3];
    const float* W_hh    = (const float*)d_in[4];
    const float* b_ih    = (const float*)d_in[5];
    const float* b_hh    = (const float*)d_in[6];
    const float* v_wn    = (const float*)d_in[7];
    const float* g_wn    = (const float*)d_in[8];
    const float* b_cls   = (const float*)d_in[9];
    float* out = (float*)d_out;

    unsigned* cnt = (unsigned*)d_ws;
    f16* b0 = (f16*)((char*)d_ws + 256);
    f16* b1 = b0 + BUFELT;

    size_t need = 256 + 2 * BUFELT * sizeof(f16);
    hipMemsetAsync(d_ws, 0, need, stream);                 // zero bufs + barrier cnt
    hipMemsetAsync(d_out, 0, (size_t)out_size * 4, stream); // head uses atomicAdd

    lstm_ws<<<NWG, 256, 0, stream>>>(cap, cap_len, embed, W_ih, W_hh, b_ih, b_hh,
                                     v_wn, g_wn, b_cls, b0, b1, cnt, out);
}